// Round 6
// baseline (490.714 us; speedup 1.0000x reference)
//
#include <hip/hip_runtime.h>
#include <hip/hip_bf16.h>
#include <math.h>

// Problem constants (fixed by the reference)
#define N_TOK 4096
#define DIM   1024
#define NEXP  16
#define HID   1536
#define TOPK2 2
#define NASSIGN (N_TOK * TOPK2)   // 8192

#define MAX_ITEMS 80   // worst-case sum_e ceil(ne/128) = 79

typedef __attribute__((ext_vector_type(8))) short short8;   // bf16x8 MFMA A/B frag
typedef __attribute__((ext_vector_type(4))) float floatx4;  // fp32x4 MFMA C/D frag
typedef unsigned short u16;

// async global->LDS, 16B per lane; LDS dest = wave-uniform base + lane*16
#define GLOAD_LDS16(gp, lp)                                                     \
    __builtin_amdgcn_global_load_lds(                                           \
        (const __attribute__((address_space(1))) unsigned int*)(gp),            \
        (__attribute__((address_space(3))) unsigned int*)(lp), 16, 0, 0)

// ---------------- fp32 -> bf16 conversion (vectorized) ----------------
__global__ void cvt_kernel(const float* __restrict__ src, u16* __restrict__ dst, int n4) {
    int i = blockIdx.x * 256 + threadIdx.x;
    if (i >= n4) return;
    float4 v = ((const float4*)src)[i];
    __hip_bfloat16 a = __float2bfloat16(v.x), b = __float2bfloat16(v.y);
    __hip_bfloat16 c = __float2bfloat16(v.z), d = __float2bfloat16(v.w);
    ushort4 o;
    o.x = *(u16*)&a; o.y = *(u16*)&b; o.z = *(u16*)&c; o.w = *(u16*)&d;
    ((ushort4*)dst)[i] = o;
}

// ---------- Router logits + top-2 + gates: tiled fp32 GEMM, no atomics ----------
__global__ __launch_bounds__(256)
void logits_topk_kernel(const float* __restrict__ x, const float* __restrict__ rw,
                        int* __restrict__ idx, float* __restrict__ gate) {
    int tb = blockIdx.x * 16;
    __shared__ float xs[16][68];
    __shared__ float rs[16][68];
    __shared__ float lg[16][17];

    int tid = threadIdx.x;
    int t = tid >> 4, e = tid & 15;
    int srow = tid >> 4, scol = (tid & 15) * 4;   // staging: one float4/thread

    float acc = 0.f;
    for (int k0 = 0; k0 < DIM; k0 += 64) {
        *(float4*)&xs[srow][scol] = *(const float4*)&x[(size_t)(tb + srow) * DIM + k0 + scol];
        *(float4*)&rs[srow][scol] = *(const float4*)&rw[(size_t)srow * DIM + k0 + scol];
        __syncthreads();
        const float2* xp = (const float2*)xs[t];
        const float2* rp = (const float2*)rs[e];
        #pragma unroll
        for (int k = 0; k < 32; k++) {
            float2 a = xp[k], b = rp[k];
            acc = fmaf(a.x, b.x, acc);
            acc = fmaf(a.y, b.y, acc);
        }
        __syncthreads();
    }
    lg[t][e] = acc;
    __syncthreads();

    if (tid < 16) {
        int n = tb + tid;
        float v0 = -3.402823466e+38f, v1 = -3.402823466e+38f;
        int i0 = 0, i1 = 0;
        #pragma unroll
        for (int ee = 0; ee < NEXP; ee++) {
            float v = lg[tid][ee];
            if (v > v0) { v1 = v0; i1 = i0; v0 = v; i0 = ee; }
            else if (v > v1) { v1 = v; i1 = ee; }
        }
        float e1 = expf(v1 - v0);
        float inv = 1.f / (1.f + e1);
        idx[2 * n] = i0; idx[2 * n + 1] = i1;
        gate[2 * n] = inv; gate[2 * n + 1] = e1 * inv;
    }
}

// ---- Plan: counts/gsum -> offsets + aux + worklist + scatter (one block) ----
__global__ __launch_bounds__(256)
void plan_kernel(const int* __restrict__ idx, const float* __restrict__ gate,
                 int* __restrict__ offsets, int* __restrict__ tlist,
                 int* __restrict__ wl, int* __restrict__ wcount,
                 float* __restrict__ aux_out) {
    __shared__ int cnt_s[16];
    __shared__ float gs_s[16];
    __shared__ int pos_s[16];
    __shared__ int offs_s[17];
    int tid = threadIdx.x;
    if (tid < 16) { cnt_s[tid] = 0; gs_s[tid] = 0.f; pos_s[tid] = 0; }
    __syncthreads();
    for (int i = tid; i < NASSIGN; i += 256) {
        int e = idx[i];
        atomicAdd(&cnt_s[e], 1);
        atomicAdd(&gs_s[e], gate[i]);
    }
    __syncthreads();
    if (tid == 0) {
        int acc = 0;
        for (int e = 0; e < NEXP; e++) { offs_s[e] = acc; acc += cnt_s[e]; }
        offs_s[NEXP] = acc;
        float tot = (float)acc;
        float s = 0.f;
        for (int e = 0; e < NEXP; e++) {
            float c = (float)cnt_s[e];
            s += (c / tot) * (gs_s[e] / fmaxf(c, 1.f));
        }
        *aux_out = 0.02f * (s / (float)NEXP);
        int m = 0;
        for (int e = 0; e < NEXP; e++) {
            int nt = (cnt_s[e] + 127) >> 7;
            for (int rt = 0; rt < nt; rt++) wl[m++] = (e << 8) | rt;
        }
        *wcount = m;
    }
    __syncthreads();
    if (tid < 17) offsets[tid] = offs_s[tid];
    for (int i = tid; i < NASSIGN; i += 256) {
        int e = idx[i];
        int p = atomicAdd(&pos_s[e], 1);
        tlist[offs_s[e] + p] = i;
    }
}

__device__ __forceinline__ float gelu_tanh(float v) {
    float v3 = v * v * v;
    float t = tanhf(0.7978845608028654f * (v + 0.044715f * v3));
    return 0.5f * v * (1.f + t);
}

// =====================================================================
// MFMA grouped GEMM, 128x128 tile, BK=64 bf16, 4 waves (each 64x64).
// BK=64 swizzle: row stride = 128 B = 8 bank-granules (row drops out of
// granule mod 8), so chunk is XORed with row&7. Stage: lane fetches global
// chunk (lane&7)^(lane>>3) of row (lane>>3); LDS slot (r,s) holds global
// chunk s^(r&7). Read of global chunk c for row r -> slot c^(r&7): 16 lanes
// with distinct r cover all 8 granules twice -> 2-way = free (m136).
// =====================================================================

// GEMM1: h[a, :] = gelu(x[tok(a)] @ w1[e]^T + b1[e]),  K=DIM=1024, N=HID=1536
__global__ __launch_bounds__(256)
void gemm1_kernel(const u16* __restrict__ xb, const u16* __restrict__ w1b,
                  const float* __restrict__ b1,
                  const int* __restrict__ offsets, const int* __restrict__ tlist,
                  const int* __restrict__ wl, const int* __restrict__ wcount,
                  u16* __restrict__ h_bf) {
    int bid = blockIdx.x;
    int item = bid / 12;
    if (item >= *wcount) return;
    int colt = bid - item * 12;
    int w = wl[item];
    int e = w >> 8, rt = w & 255;
    int beg = offsets[e], ne = offsets[e + 1] - beg;
    int row0 = rt * 128, col0 = colt * 128;

    __shared__ u16 As[128 * 64];
    __shared__ u16 Bs[128 * 64];

    int tid = threadIdx.x;
    int wave = tid >> 6, lane = tid & 63;
    int wm = wave & 1, wn = wave >> 1;

    // Staging: 4 insts each for A and B; inst q covers rows wave*32+q*8+(lane>>3),
    // global k-chunk ((lane&7)^(lane>>3))*8 u16.
    int koff = ((lane & 7) ^ (lane >> 3)) * 8;
    const u16* aptr[4];
    const u16* bptr[4];
    #pragma unroll
    for (int q = 0; q < 4; q++) {
        int lrow = wave * 32 + q * 8 + (lane >> 3);
        int gi2 = (row0 + lrow < ne) ? (beg + row0 + lrow) : beg;  // clamp OOB
        int tok = tlist[gi2] >> 1;
        aptr[q] = xb + (size_t)tok * DIM + koff;
        bptr[q] = w1b + (size_t)(e * HID + col0 + lrow) * DIM + koff;
    }

    // Fragment read LDS chunk offsets (u16): global chunk g*4+(lane>>4), row key lane&7
    int rc[2];
    rc[0] = (((lane >> 4) ^ (lane & 7)) * 8);
    rc[1] = (((4 + (lane >> 4)) ^ (lane & 7)) * 8);

    floatx4 acc[4][4] = {};
    for (int k0 = 0; k0 < DIM; k0 += 64) {
        #pragma unroll
        for (int q = 0; q < 4; q++)
            GLOAD_LDS16(aptr[q] + k0, &As[(wave * 32 + q * 8) * 64]);
        #pragma unroll
        for (int q = 0; q < 4; q++)
            GLOAD_LDS16(bptr[q] + k0, &Bs[(wave * 32 + q * 8) * 64]);
        __syncthreads();
        #pragma unroll
        for (int g = 0; g < 2; g++) {
            short8 af[4], bf_[4];
            #pragma unroll
            for (int mi = 0; mi < 4; mi++)
                af[mi] = *(const short8*)&As[(wm * 64 + mi * 16 + (lane & 15)) * 64 + rc[g]];
            #pragma unroll
            for (int nj = 0; nj < 4; nj++)
                bf_[nj] = *(const short8*)&Bs[(wn * 64 + nj * 16 + (lane & 15)) * 64 + rc[g]];
            #pragma unroll
            for (int mi = 0; mi < 4; mi++)
                #pragma unroll
                for (int nj = 0; nj < 4; nj++)
                    acc[mi][nj] = __builtin_amdgcn_mfma_f32_16x16x32_bf16(af[mi], bf_[nj], acc[mi][nj], 0, 0, 0);
        }
        __syncthreads();
    }

    // Epilogue: C/D layout col=lane&15, row=(lane>>4)*4+reg
    #pragma unroll
    for (int mi = 0; mi < 4; mi++) {
        #pragma unroll
        for (int r = 0; r < 4; r++) {
            int lrow = wm * 64 + mi * 16 + (lane >> 4) * 4 + r;
            if (row0 + lrow >= ne) continue;
            size_t orow = (size_t)(beg + row0 + lrow);
            #pragma unroll
            for (int nj = 0; nj < 4; nj++) {
                int col = col0 + wn * 64 + nj * 16 + (lane & 15);
                float v = acc[mi][nj][r] + b1[e * HID + col];
                __hip_bfloat16 hb = __float2bfloat16(gelu_tanh(v));
                h_bf[orow * HID + col] = *(u16*)&hb;
            }
        }
    }
}

// GEMM2: out[tok(a)] += gate(a) * (h[a] @ w2[e]^T + b2[e]),  K=HID=1536 split 2x768
__global__ __launch_bounds__(256)
void gemm2_kernel(const u16* __restrict__ h_bf, const u16* __restrict__ w2b,
                  const float* __restrict__ b2,
                  const int* __restrict__ offsets, const int* __restrict__ tlist,
                  const int* __restrict__ wl, const int* __restrict__ wcount,
                  const float* __restrict__ gate, float* __restrict__ out) {
    int bid = blockIdx.x;
    int item = bid >> 4;
    if (item >= *wcount) return;
    int colt = (bid >> 1) & 7;
    int ks = bid & 1;                      // K-split index
    int w = wl[item];
    int e = w >> 8, rt = w & 255;
    int beg = offsets[e], ne = offsets[e + 1] - beg;
    int row0 = rt * 128, col0 = colt * 128;
    int kbeg = ks * (HID / 2);             // 0 or 768

    __shared__ u16 As[128 * 64];
    __shared__ u16 Bs[128 * 64];

    int tid = threadIdx.x;
    int wave = tid >> 6, lane = tid & 63;
    int wm = wave & 1, wn = wave >> 1;

    int koff = ((lane & 7) ^ (lane >> 3)) * 8;
    const u16* aptr[4];
    const u16* bptr[4];
    #pragma unroll
    for (int q = 0; q < 4; q++) {
        int lrow = wave * 32 + q * 8 + (lane >> 3);
        int gi2 = (row0 + lrow < ne) ? (beg + row0 + lrow) : beg;
        aptr[q] = h_bf + (size_t)gi2 * HID + kbeg + koff;
        bptr[q] = w2b + (size_t)(e * DIM + col0 + lrow) * HID + kbeg + koff;
    }

    int rc[2];
    rc[0] = (((lane >> 4) ^ (lane & 7)) * 8);
    rc[1] = (((4 + (lane >> 4)) ^ (lane & 7)) * 8);

    floatx4 acc[4][4] = {};
    for (int k0 = 0; k0 < HID / 2; k0 += 64) {
        #pragma unroll
        for (int q = 0; q < 4; q++)
            GLOAD_LDS16(aptr[q] + k0, &As[(wave * 32 + q * 8) * 64]);
        #pragma unroll
        for (int q = 0; q < 4; q++)
            GLOAD_LDS16(bptr[q] + k0, &Bs[(wave * 32 + q * 8) * 64]);
        __syncthreads();
        #pragma unroll
        for (int g = 0; g < 2; g++) {
            short8 af[4], bf_[4];
            #pragma unroll
            for (int mi = 0; mi < 4; mi++)
                af[mi] = *(const short8*)&As[(wm * 64 + mi * 16 + (lane & 15)) * 64 + rc[g]];
            #pragma unroll
            for (int nj = 0; nj < 4; nj++)
                bf_[nj] = *(const short8*)&Bs[(wn * 64 + nj * 16 + (lane & 15)) * 64 + rc[g]];
            #pragma unroll
            for (int mi = 0; mi < 4; mi++)
                #pragma unroll
                for (int nj = 0; nj < 4; nj++)
                    acc[mi][nj] = __builtin_amdgcn_mfma_f32_16x16x32_bf16(af[mi], bf_[nj], acc[mi][nj], 0, 0, 0);
        }
        __syncthreads();
    }

    #pragma unroll
    for (int mi = 0; mi < 4; mi++) {
        #pragma unroll
        for (int r = 0; r < 4; r++) {
            int lrow = wm * 64 + mi * 16 + (lane >> 4) * 4 + r;
            if (row0 + lrow >= ne) continue;
            int t = tlist[beg + row0 + lrow];
            float g = gate[t];
            int tok = t >> 1;
            #pragma unroll
            for (int nj = 0; nj < 4; nj++) {
                int col = col0 + wn * 64 + nj * 16 + (lane & 15);
                float v = acc[mi][nj][r];
                if (ks == 0) v += b2[e * DIM + col];   // bias carried by split 0
                atomicAdd(&out[(size_t)tok * DIM + col], g * v);
            }
        }
    }
}

extern "C" void kernel_launch(void* const* d_in, const int* in_sizes, int n_in,
                              void* d_out, int out_size, void* d_ws, size_t ws_size,
                              hipStream_t stream) {
    const float* x  = (const float*)d_in[0];
    const float* rw = (const float*)d_in[1];
    const float* w1 = (const float*)d_in[2];
    const float* b1 = (const float*)d_in[3];
    const float* w2 = (const float*)d_in[4];
    const float* b2 = (const float*)d_in[5];
    float* out = (float*)d_out;   // fp32 output [N*D main | 1 aux]

    // ---- workspace layout (bytes) ----
    char* ws = (char*)d_ws;
    int*   offsets = (int*)(ws + 192);        // 17
    int*   wcount  = (int*)(ws + 384);        // 1
    int*   wl      = (int*)(ws + 512);        // up to 128
    int*   idx     = (int*)(ws + 4096);                               // 32 KB
    float* gate    = (float*)(ws + 4096 + 4 * NASSIGN);               // 32 KB
    int*   tlist   = (int*)(ws + 4096 + 8 * NASSIGN);                 // 32 KB
    u16*   x_bf    = (u16*)(ws + (128 << 10));                        // 8 MB
    u16*   h_bf    = x_bf + (size_t)N_TOK * DIM;                      // 25.2 MB
    u16*   w_bf    = h_bf + (size_t)NASSIGN * HID;                    // 50.3 MB (w1 then w2)

    hipMemsetAsync(d_out, 0, (size_t)out_size * 4, stream); // zero for atomic combine

    cvt_kernel<<<(N_TOK * DIM / 4 + 255) / 256, 256, 0, stream>>>(x, x_bf, N_TOK * DIM / 4);
    cvt_kernel<<<(NEXP * HID * DIM / 4 + 255) / 256, 256, 0, stream>>>(w1, w_bf, NEXP * HID * DIM / 4);

    logits_topk_kernel<<<N_TOK / 16, 256, 0, stream>>>(x, rw, idx, gate);
    plan_kernel<<<1, 256, 0, stream>>>(idx, gate, offsets, tlist, wl, wcount,
                                       out + (size_t)N_TOK * DIM);

    gemm1_kernel<<<MAX_ITEMS * 12, 256, 0, stream>>>(
        x_bf, w_bf, b1, offsets, tlist, wl, wcount, h_bf);

    cvt_kernel<<<(NEXP * DIM * HID / 4 + 255) / 256, 256, 0, stream>>>(w2, w_bf, NEXP * DIM * HID / 4);

    gemm2_kernel<<<MAX_ITEMS * 16, 256, 0, stream>>>(
        h_bf, w_bf, b2, offsets, tlist, wl, wcount, gate, out);
}